// Round 3
// baseline (132.525 us; speedup 1.0000x reference)
//
#include <hip/hip_runtime.h>
#include <hip/hip_bf16.h>

typedef __attribute__((ext_vector_type(8)))  _Float16 half8;
typedef __attribute__((ext_vector_type(2)))  _Float16 half2v;
typedef __attribute__((ext_vector_type(16))) float f32x16;
typedef __attribute__((ext_vector_type(4)))  unsigned int uint4v;
typedef unsigned int   uint32;
typedef unsigned short u16;

#define DEV __device__ __forceinline__

constexpr int S   = 2048;
constexpr int D   = 128;
constexpr int QB  = 256;   // q rows per block (8 waves x 32)
constexpr int KVB = 64;    // kv rows per tile
constexpr int NT  = S / KVB;  // 32
constexpr float LOG2E = 1.4426950408889634f;

// fp32 -> fp16 (hardware v_cvt_f16_f32, RNE). fp16 mantissa (10b) cuts the
// QK^T score error 8x vs bf16 -- that was the 0.148-vs-0.104 absmax gap.
DEV uint32 pk2(float a, float b) {
  half2v h = { (_Float16)a, (_Float16)b };
  return __builtin_bit_cast(uint32, h);
}
DEV u16 tof16(float a) {
  _Float16 h = (_Float16)a;
  return __builtin_bit_cast(u16, h);
}

// Flash attention fwd, fp32 in/out, fp16 MFMA compute.
// Layout notes (mfma_f32_32x32x16_f16):
//   A-frag: row = l&31, k = (l>>5)*8 + j (8 contiguous f16 -> b128)
//   B-frag: col = l&31, k = (l>>5)*8 + j
//   C/D:    col = l&31, row = (r&3) + 8*(r>>2) + 4*(l>>5)   [m74/m101]
// We compute S^T = K*Q^T (rows kv, cols q) so softmax over kv is
// in-register: lane pair {l, l^32} holds the full 64-kv column.
__global__ __launch_bounds__(512, 2)
void attn_fwd(const float* __restrict__ Qg, const float* __restrict__ Kg,
              const float* __restrict__ Vg, float* __restrict__ Og) {
  // K tiles: f16 [64][128] row-major, 256B rows, XOR-swizzled granules
  // V^T tiles: f16 [128][64], 128B rows, XOR-swizzled
  __shared__ __align__(16) char kb[2][64 * 256];
  __shared__ __align__(16) char vb[2][128 * 128];

  const int tid = threadIdx.x;
  const int w  = tid >> 6;
  const int l  = tid & 63;
  const int lo = l & 31;
  const int h  = l >> 5;

  // XCD-aware swizzle: 256 blocks -> 8 XCD chunks of 32 (= 4 heads each)
  const int idb = blockIdx.x;
  const int swz = (idb & 7) * 32 + (idb >> 3);
  const int bh  = swz >> 3;   // [0,32) batch*head
  const int qb  = swz & 7;    // [0,8)  q block

  const size_t base = (size_t)bh * S * D;
  const float4* __restrict__ Q4 = (const float4*)(Qg + base);
  const float4* __restrict__ K4 = (const float4*)(Kg + base);
  const float4* __restrict__ V4 = (const float4*)(Vg + base);

  // ---- Q fragments (held in registers for whole kernel) ----
  half8 qf[8];
  {
    const int q = qb * QB + w * 32 + lo;
    #pragma unroll
    for (int kc = 0; kc < 8; ++kc) {
      const int f4 = q * 32 + kc * 4 + h * 2;  // d0 = kc*16 + h*8
      float4 a = Q4[f4];
      float4 b = Q4[f4 + 1];
      uint4v uu = { pk2(a.x, a.y), pk2(a.z, a.w), pk2(b.x, b.y), pk2(b.z, b.w) };
      qf[kc] = __builtin_bit_cast(half8, uu);
    }
  }

  f32x16 acc0 = {}, acc1 = {}, acc2 = {}, acc3 = {};  // O^T, d tiles 0..3
  float m_run = -3.0e38f, l_run = 0.f;

  // staging work assignment
  const int krow = tid >> 4;          // [0,32) K row (and +32)
  const int kgr  = tid & 15;          // [0,16) 16B granule in 256B K row
  const int vc   = tid & 1;           // V: d half
  const int vkv  = (tid & 127) >> 1;  // V: kv row [0,64)
  const int vq   = tid >> 7;          // V: d quarter [0,4)

  float4 kreg[4], vreg[4];

  auto stage_issue = [&](int t) {  // global -> regs (fp32), issued early (T14)
    const int r0 = t * KVB;
    #pragma unroll
    for (int i = 0; i < 2; ++i) {
      const int gi = (r0 + i * 32 + krow) * 32 + kgr * 2;
      kreg[2 * i]     = K4[gi];
      kreg[2 * i + 1] = K4[gi + 1];
    }
    #pragma unroll
    for (int i = 0; i < 4; ++i)
      vreg[i] = V4[(r0 + vkv) * 32 + vc * 16 + vq * 4 + i];
  };

  auto stage_write = [&](int bsel) {  // cvt + regs -> LDS (f16, swizzled)
    char* kd = kb[bsel];
    char* vd = vb[bsel];
    #pragma unroll
    for (int i = 0; i < 2; ++i) {
      const int row = i * 32 + krow;
      uint4v uu = { pk2(kreg[2*i].x,   kreg[2*i].y),   pk2(kreg[2*i].z,   kreg[2*i].w),
                    pk2(kreg[2*i+1].x, kreg[2*i+1].y), pk2(kreg[2*i+1].z, kreg[2*i+1].w) };
      *(uint4v*)(kd + row * 256 + ((kgr * 16) ^ ((row & 7) << 4))) = uu;
    }
    #pragma unroll
    for (int i = 0; i < 4; ++i) {
      const float vv[4] = { vreg[i].x, vreg[i].y, vreg[i].z, vreg[i].w };
      #pragma unroll
      for (int j = 0; j < 4; ++j) {
        const int d = vc * 64 + vq * 16 + i * 4 + j;   // V^T row
        *(u16*)(vd + d * 128 + ((vkv * 2) ^ ((d & 7) << 4))) = tof16(vv[j]);
      }
    }
  };

  stage_issue(0);
  stage_write(0);
  __syncthreads();

  for (int t = 0; t < NT; ++t) {
    const char* kcur = kb[t & 1];
    const char* vcur = vb[t & 1];
    if (t + 1 < NT) stage_issue(t + 1);  // loads in flight during compute

    // ---- S^T = K * Q^T over d (8 chunks of 16) ----
    f32x16 st0 = {}, st1 = {};
    #pragma unroll
    for (int kc = 0; kc < 8; ++kc) {
      const int boff = kc * 32 + h * 16;
      const int sw = (lo & 7) << 4;
      half8 kf0 = *(const half8*)(kcur + lo * 256        + (boff ^ sw));
      half8 kf1 = *(const half8*)(kcur + (32 + lo) * 256 + (boff ^ sw));
      st0 = __builtin_amdgcn_mfma_f32_32x32x16_f16(kf0, qf[kc], st0, 0, 0, 0);
      st1 = __builtin_amdgcn_mfma_f32_32x32x16_f16(kf1, qf[kc], st1, 0, 0, 0);
    }

    // ---- online softmax: lane holds 32 kv of column q=lo; partner l^32 rest ----
    float mA = fmaxf(st0[0], st1[0]), mB = fmaxf(st0[1], st1[1]);
    float mC = fmaxf(st0[2], st1[2]), mD = fmaxf(st0[3], st1[3]);
    #pragma unroll
    for (int r = 4; r < 16; r += 4) {
      mA = fmaxf(mA, fmaxf(st0[r],   st1[r]));
      mB = fmaxf(mB, fmaxf(st0[r+1], st1[r+1]));
      mC = fmaxf(mC, fmaxf(st0[r+2], st1[r+2]));
      mD = fmaxf(mD, fmaxf(st0[r+3], st1[r+3]));
    }
    float mloc = fmaxf(fmaxf(mA, mB), fmaxf(mC, mD));
    mloc = fmaxf(mloc, __shfl_xor(mloc, 32, 64));
    const float m_new = fmaxf(m_run, mloc);
    const float alpha = exp2f((m_run - m_new) * LOG2E);
    const float mm = m_new * LOG2E;

    float sA = 0.f, sB = 0.f, sC = 0.f, sD = 0.f;
    #pragma unroll
    for (int r = 0; r < 16; r += 4) {
      st0[r]   = exp2f(st0[r]   * LOG2E - mm); sA += st0[r];
      st0[r+1] = exp2f(st0[r+1] * LOG2E - mm); sB += st0[r+1];
      st0[r+2] = exp2f(st0[r+2] * LOG2E - mm); sC += st0[r+2];
      st0[r+3] = exp2f(st0[r+3] * LOG2E - mm); sD += st0[r+3];
      st1[r]   = exp2f(st1[r]   * LOG2E - mm); sA += st1[r];
      st1[r+1] = exp2f(st1[r+1] * LOG2E - mm); sB += st1[r+1];
      st1[r+2] = exp2f(st1[r+2] * LOG2E - mm); sC += st1[r+2];
      st1[r+3] = exp2f(st1[r+3] * LOG2E - mm); sD += st1[r+3];
    }
    float lsum = (sA + sB) + (sC + sD);
    lsum += __shfl_xor(lsum, 32, 64);
    l_run = l_run * alpha + lsum;
    m_run = m_new;
    #pragma unroll
    for (int r = 0; r < 16; ++r) {
      acc0[r] *= alpha; acc1[r] *= alpha; acc2[r] *= alpha; acc3[r] *= alpha;
    }

    // ---- P^T -> f16 B-fragments (lane needs kv = ks*16 + h*8 + j) ----
    // Own regs give kv {4h + (r&3) + 8*(r>>2)}; partner (l^32) fills the gap.
    half8 pb[4];
    #define PACK_KS(SRC, RB, DST) { \
      uint32 u01 = pk2(SRC[RB+0], SRC[RB+1]); \
      uint32 u23 = pk2(SRC[RB+2], SRC[RB+3]); \
      uint32 v01 = pk2(SRC[RB+4], SRC[RB+5]); \
      uint32 v23 = pk2(SRC[RB+6], SRC[RB+7]); \
      uint32 su01 = (uint32)__shfl_xor((int)u01, 32, 64); \
      uint32 su23 = (uint32)__shfl_xor((int)u23, 32, 64); \
      uint32 sv01 = (uint32)__shfl_xor((int)v01, 32, 64); \
      uint32 sv23 = (uint32)__shfl_xor((int)v23, 32, 64); \
      uint4v uu = { h ? sv01 : u01, h ? sv23 : u23, \
                    h ? v01 : su01, h ? v23 : su23 }; \
      DST = __builtin_bit_cast(half8, uu); }
    PACK_KS(st0, 0, pb[0])
    PACK_KS(st0, 8, pb[1])
    PACK_KS(st1, 0, pb[2])
    PACK_KS(st1, 8, pb[3])
    #undef PACK_KS

    // ---- O^T += V^T * P^T ----
    #pragma unroll
    for (int ks = 0; ks < 4; ++ks) {
      const int boff = ks * 32 + h * 16;
      #define PVSTEP(DT, ACC) { const int rr = DT * 32 + lo; \
        half8 vf = *(const half8*)(vcur + rr * 128 + (boff ^ ((rr & 7) << 4))); \
        ACC = __builtin_amdgcn_mfma_f32_32x32x16_f16(vf, pb[ks], ACC, 0, 0, 0); }
      PVSTEP(0, acc0) PVSTEP(1, acc1) PVSTEP(2, acc2) PVSTEP(3, acc3)
      #undef PVSTEP
    }

    __syncthreads();                         // everyone done reading cur
    if (t + 1 < NT) stage_write((t + 1) & 1);
    __syncthreads();                         // next tile visible
  }

  // ---- epilogue: O = O^T / l, store fp32 ----
  const float rl = 1.0f / l_run;
  const int q = qb * QB + w * 32 + lo;
  float* Op = Og + base + (size_t)q * D;
  auto store_dt = [&](int dt, const f32x16& a) {
    #pragma unroll
    for (int rq = 0; rq < 4; ++rq) {
      // reg rq*4+c -> d = dt*32 + 8*rq + 4*h + c
      float4 o = { a[rq*4+0]*rl, a[rq*4+1]*rl, a[rq*4+2]*rl, a[rq*4+3]*rl };
      *(float4*)(Op + dt * 32 + rq * 8 + h * 4) = o;
    }
  };
  store_dt(0, acc0); store_dt(1, acc1); store_dt(2, acc2); store_dt(3, acc3);
}

extern "C" void kernel_launch(void* const* d_in, const int* in_sizes, int n_in,
                              void* d_out, int out_size, void* d_ws, size_t ws_size,
                              hipStream_t stream) {
  (void)in_sizes; (void)n_in; (void)out_size; (void)d_ws; (void)ws_size;
  const float* Q = (const float*)d_in[0];
  const float* K = (const float*)d_in[1];
  const float* V = (const float*)d_in[2];
  float* O = (float*)d_out;
  attn_fwd<<<dim3(256), dim3(512), 0, stream>>>(Q, K, V, O);
}